// Round 8
// baseline (41.575 us; speedup 1.0000x reference)
//
#include <hip/hip_runtime.h>

// Keep IEEE mul-then-add semantics (match JAX/XLA fp32 reference; near-tie
// d0<d1 coset decisions are sensitive to contraction/reassociation).
#pragma clang fp contract(off)

#define TINY_EPS 1.1920928955078125e-07f  // np.finfo(float32).eps

typedef float f4 __attribute__((ext_vector_type(4)));
typedef float f2 __attribute__((ext_vector_type(2)));  // -> v_pk_*_f32

// 1 point per thread. Cosets A (z) and B (z-0.5) processed as the two halves
// of <2 x float> so elementwise sub/add and the distance accumulation lower
// to packed v_pk_add_f32 / v_pk_mul_f32 (2 IEEE fp32 ops per VALU issue).
// Store path (R7): transpose via LDS -> lane-contiguous full-line nt stores.
__global__ void __launch_bounds__(256)
e8_quant_kernel(const float* __restrict__ x, const float* __restrict__ beta_p,
                const float* __restrict__ eps, float* __restrict__ out, int N) {
    __shared__ float tile[8][257];  // +1 pad: writes conflict-free, reads 2-way (free)
    int tid = threadIdx.x;
    int i   = blockIdx.x * 256 + tid;
    bool full_block = ((blockIdx.x + 1) * 256) <= N;  // block-uniform
    if (!full_block && i >= N) return;                // no barrier on this path

    float beta = *beta_p;
    float e[8];
#pragma unroll
    for (int j = 0; j < 8; ++j) e[j] = eps[j];  // uniform

    const f4* xp = reinterpret_cast<const f4*>(x) + (size_t)i * 2;
    f4 a = xp[0];
    f4 b = xp[1];
    float z[8] = {a.x, a.y, a.z, a.w, b.x, b.y, b.z, b.w};

    if (beta == 1.0f) {  // uniform branch; bit-exact: x/1.0 == x
#pragma unroll
        for (int j = 0; j < 8; ++j) z[j] = z[j] + e[j];
    } else {
#pragma unroll
        for (int j = 0; j < 8; ++j) z[j] = z[j] / beta + e[j];  // IEEE div
    }

    // ---- packed custom_round for both cosets: .x = A (z), .y = B (z-0.5) ----
    f2 fpk[8], dpk[8];              // rounded values; signed residuals (exact)
    f2 fsum = {0.0f, 0.0f};
#pragma unroll
    for (int j = 0; j < 8; ++j) {
        f2 xv = {z[j], z[j] - 0.5f};
        f2 cs = {__builtin_copysignf(TINY_EPS, xv.x),
                 __builtin_copysignf(TINY_EPS, xv.y)};
        f2 t  = xv - cs;                         // pk: x - sign(x)*eps
        f2 u  = t + 0.5f;                        // pk
        f2 fv = {floorf(u.x), floorf(u.y)};      // custom_round
        fpk[j] = fv;
        dpk[j] = xv - fv;                        // pk; d = x-f is EXACT
        fsum   = fsum + fv;                      // pk; exact small ints
    }
    bool oddA = (((int)fsum.x) & 1) != 0;
    bool oddB = (((int)fsum.y) & 1) != 0;

    // ---- first-max argmax per coset on |d| (abs folds into cmp modifiers) ----
    int   kA = 0,        kB = 0;
    float bdA = dpk[0].x, fkA = fpk[0].x;
    float bdB = dpk[0].y, fkB = fpk[0].y;
#pragma unroll
    for (int j = 1; j < 8; ++j) {
        bool bA = fabsf(dpk[j].x) > fabsf(bdA);  // strict: first max wins
        bdA = bA ? dpk[j].x : bdA;
        fkA = bA ? fpk[j].x : fkA;
        kA  = bA ? j : kA;
        bool bB = fabsf(dpk[j].y) > fabsf(bdB);
        bdB = bB ? dpk[j].y : bdB;
        fkB = bB ? fpk[j].y : fkB;
        kB  = bB ? j : kB;
    }
    // up = x>=0 ? f<x : f<=x. Since d=x-f exact: f<x <=> d>0, f<=x <=> d>=0,
    // and sign(x): f>0 -> x>0, f<0 -> x<0, f==0 -> sign(x)=sign(d).
    // Collapses to: up = (f<0) ? d>=0 : d>0.   (verified incl. |d|~0.5+ulp)
    bool  upA    = (fkA < 0.0f) ? (bdA >= 0.0f) : (bdA > 0.0f);
    float adjA   = fkA + (upA ? 1.0f : -1.0f);               // exact int
    bool  upB    = (fkB < 0.0f) ? (bdB >= 0.0f) : (bdB > 0.0f);
    float adjB05 = (fkB + (upB ? 1.0f : -1.0f)) + 0.5f;      // exact half-int

    // ---- distances (packed {d0,d1}) + lattice-point selection ----
    // Reference: d1 terms are z - (fB + 0.5)  [z-BASED, not (z-0.5)-fB: the
    // two differ by 1 ulp when fl(z-0.5) is inexact -> coset flip risk].
    f2 dacc = {0.0f, 0.0f};
    float yA[8], yB[8];
#pragma unroll
    for (int j = 0; j < 8; ++j) {
        bool  mA  = oddA && (j == kA);
        bool  mB  = oddB && (j == kB);
        float yBj = fpk[j].y + 0.5f;                  // exact half-int
        float vA  = mA ? __fsub_rn(z[j], adjA)   : dpk[j].x;  // == ref t0
        float vB  = mB ? __fsub_rn(z[j], adjB05) : __fsub_rn(z[j], yBj);  // ref t1
        f2 v = {vA, vB};
        dacc = dacc + v * v;   // pk_mul then pk_add (contract off): ref order
        yA[j] = mA ? adjA   : fpk[j].x;
        yB[j] = mB ? adjB05 : yBj;
    }
    bool pick0 = dacc.x < dacc.y;  // ties -> y1, matching jnp.where(d0<d1,...)

    float q[8];
#pragma unroll
    for (int j = 0; j < 8; ++j)
        q[j] = __fmul_rn(beta, pick0 ? yA[j] : yB[j]);

    // ---- store: LDS transpose -> lane-contiguous full-line nt stores ----
    if (full_block) {
#pragma unroll
        for (int j = 0; j < 8; ++j) tile[j][tid] = q[j];
        __syncthreads();
        int wave = tid >> 6, lane = tid & 63;
        int wb   = wave << 6;
        f4* op   = reinterpret_cast<f4*>(out) + (size_t)blockIdx.x * 512 + wave * 128;
#pragma unroll
        for (int c = 0; c < 2; ++c) {
            int p = wb + c * 32 + (lane >> 1);  // source point (block-local)
            int h = (lane & 1) << 2;            // q[0..3] or q[4..7]
            f4 v = {tile[h + 0][p], tile[h + 1][p], tile[h + 2][p], tile[h + 3][p]};
            __builtin_nontemporal_store(v, op + c * 64 + lane);
        }
    } else {
        // tail fallback (never taken at N=4e6): plain cached stores
        f4* op = reinterpret_cast<f4*>(out) + (size_t)i * 2;
        f4 s0 = {q[0], q[1], q[2], q[3]};
        f4 s1 = {q[4], q[5], q[6], q[7]};
        op[0] = s0;
        op[1] = s1;
    }
}

extern "C" void kernel_launch(void* const* d_in, const int* in_sizes, int n_in,
                              void* d_out, int out_size, void* d_ws, size_t ws_size,
                              hipStream_t stream) {
    const float* x      = (const float*)d_in[0];
    const float* beta_p = (const float*)d_in[1];
    const float* eps    = (const float*)d_in[2];
    float*       out    = (float*)d_out;

    int N     = in_sizes[0] / 8;  // 4,000,000 points
    int block = 256;
    int grid  = (N + block - 1) / block;
    hipLaunchKernelGGL(e8_quant_kernel, dim3(grid), dim3(block), 0, stream,
                       x, beta_p, eps, out, N);
}

// Round 9
// 41.212 us; speedup vs baseline: 1.0088x; 1.0088x over previous
//
#include <hip/hip_runtime.h>

// Keep IEEE mul-then-add semantics (match JAX/XLA fp32 reference; near-tie
// d0<d1 coset decisions are sensitive to contraction/reassociation).
#pragma clang fp contract(off)

#define TINY_EPS 1.1920928955078125e-07f  // np.finfo(float32).eps

typedef float f4 __attribute__((ext_vector_type(4)));
typedef float f2 __attribute__((ext_vector_type(2)));  // -> v_pk_*_f32 where packable

// 1 point per thread. Cosets A (z) and B (z-0.5) both go through the exact
// packed custom_round (B may NOT be derived from A's residuals: when
// |dA| < ulp(fA-0.5)/2, fl(z-0.5) is an exact half-integer tie and the
// reference's eps-rule decides by sign, not by dA).
// Selection is built reference-order: y_j selected FIRST, then t = z - y_j.
// Store path (R7): LDS transpose -> lane-contiguous full-line nt stores.
__global__ void __launch_bounds__(256)
e8_quant_kernel(const float* __restrict__ x, const float* __restrict__ beta_p,
                const float* __restrict__ eps, float* __restrict__ out, int N) {
    __shared__ float tile[8][257];  // +1 pad: writes conflict-free, reads 2-way (free)
    int tid = threadIdx.x;
    int i   = blockIdx.x * 256 + tid;
    bool full_block = ((blockIdx.x + 1) * 256) <= N;  // block-uniform
    if (!full_block && i >= N) return;                // no barrier on this path

    float beta = *beta_p;
    bool  b1   = (beta == 1.0f);  // uniform
    float e[8];
#pragma unroll
    for (int j = 0; j < 8; ++j) e[j] = eps[j];  // uniform

    const f4* xp = reinterpret_cast<const f4*>(x) + (size_t)i * 2;
    f4 a = xp[0];
    f4 b = xp[1];
    float z[8] = {a.x, a.y, a.z, a.w, b.x, b.y, b.z, b.w};

    if (b1) {  // bit-exact: x/1.0 == x
#pragma unroll
        for (int j = 0; j < 8; ++j) z[j] = z[j] + e[j];
    } else {
#pragma unroll
        for (int j = 0; j < 8; ++j) z[j] = z[j] / beta + e[j];  // IEEE div
    }

    // ---- packed custom_round for both cosets: .x = A (z), .y = B (z-0.5) ----
    f2 fpk[8], dpk[8];
    f2 fsum = {0.0f, 0.0f};
#pragma unroll
    for (int j = 0; j < 8; ++j) {
        f2 xv = {z[j], z[j] - 0.5f};
        f2 cs = {__builtin_copysignf(TINY_EPS, xv.x),
                 __builtin_copysignf(TINY_EPS, xv.y)};
        f2 t  = xv - cs;                         // x - sign(x)*eps
        f2 u  = t + 0.5f;
        f2 fv = {floorf(u.x), floorf(u.y)};      // custom_round
        fpk[j] = fv;
        dpk[j] = xv - fv;                        // signed residual (exact)
        fsum   = fsum + fv;                      // exact small ints
    }
    bool oddA = (((int)fsum.x) & 1) != 0;  // matches jnp.mod parity (neg incl.)
    bool oddB = (((int)fsum.y) & 1) != 0;

    // ---- first-max argmax per coset on |d| (abs folds into cmp modifiers) ----
    int   kA = 0,        kB = 0;
    float bdA = dpk[0].x, fkA = fpk[0].x;
    float bdB = dpk[0].y, fkB = fpk[0].y;
#pragma unroll
    for (int j = 1; j < 8; ++j) {
        bool bA = fabsf(dpk[j].x) > fabsf(bdA);  // strict: first max wins
        bdA = bA ? dpk[j].x : bdA;
        fkA = bA ? fpk[j].x : fkA;
        kA  = bA ? j : kA;
        bool bB = fabsf(dpk[j].y) > fabsf(bdB);
        bdB = bB ? dpk[j].y : bdB;
        fkB = bB ? fpk[j].y : fkB;
        kB  = bB ? j : kB;
    }
    // up = x>=0 ? f<x : f<=x; with d=x-f exact: up = (f<0) ? d>=0 : d>0.
    bool  upA    = (fkA < 0.0f) ? (bdA >= 0.0f) : (bdA > 0.0f);
    float adjA   = fkA + (upA ? 1.0f : -1.0f);               // exact int
    bool  upB    = (fkB < 0.0f) ? (bdB >= 0.0f) : (bdB > 0.0f);
    float adjB05 = (fkB + (upB ? 1.0f : -1.0f)) + 0.5f;      // exact half-int
                                                             // == ref (fB+adj)+0.5
    // k'-trick: fold odd into the index (8 never matches j in [0,8))
    int kA2 = oddA ? kA : 8;
    int kB2 = oddB ? kB : 8;

    // ---- build y (ref order: select first), distances t = z - y ----
    f2 dacc = {0.0f, 0.0f};
    float yAs[8], yBs[8];
#pragma unroll
    for (int j = 0; j < 8; ++j) {
        bool  mA  = (j == kA2);                 // single cmp per coset
        bool  mB  = (j == kB2);
        float yA  = mA ? adjA : fpk[j].x;       // == ref y0_j
        float yBh = fpk[j].y + 0.5f;            // exact half-int
        float yB  = mB ? adjB05 : yBh;          // == ref y1_j
        yAs[j] = yA;
        yBs[j] = yB;
        f2 v = {__fsub_rn(z[j], yA),            // == ref t0
                __fsub_rn(z[j], yB)};           // == ref t1 (z-based)
        dacc = dacc + v * v;  // pk mul, pk add; sequential j order, contract off
    }
    bool pick0 = dacc.x < dacc.y;  // ties -> y1, matching jnp.where(d0<d1,...)

    float q[8];
    if (b1) {  // 1.0*y == y exactly (incl. -0)
#pragma unroll
        for (int j = 0; j < 8; ++j) q[j] = pick0 ? yAs[j] : yBs[j];
    } else {
#pragma unroll
        for (int j = 0; j < 8; ++j) q[j] = __fmul_rn(beta, pick0 ? yAs[j] : yBs[j]);
    }

    // ---- store: LDS transpose -> lane-contiguous full-line nt stores ----
    if (full_block) {
#pragma unroll
        for (int j = 0; j < 8; ++j) tile[j][tid] = q[j];
        __syncthreads();
        int wave = tid >> 6, lane = tid & 63;
        int wb   = wave << 6;
        f4* op   = reinterpret_cast<f4*>(out) + (size_t)blockIdx.x * 512 + wave * 128;
#pragma unroll
        for (int c = 0; c < 2; ++c) {
            int p = wb + c * 32 + (lane >> 1);  // source point (block-local)
            int h = (lane & 1) << 2;            // q[0..3] or q[4..7]
            f4 v = {tile[h + 0][p], tile[h + 1][p], tile[h + 2][p], tile[h + 3][p]};
            __builtin_nontemporal_store(v, op + c * 64 + lane);
        }
    } else {
        // tail fallback (never taken at N=4e6): plain cached stores
        f4* op = reinterpret_cast<f4*>(out) + (size_t)i * 2;
        f4 s0 = {q[0], q[1], q[2], q[3]};
        f4 s1 = {q[4], q[5], q[6], q[7]};
        op[0] = s0;
        op[1] = s1;
    }
}

extern "C" void kernel_launch(void* const* d_in, const int* in_sizes, int n_in,
                              void* d_out, int out_size, void* d_ws, size_t ws_size,
                              hipStream_t stream) {
    const float* x      = (const float*)d_in[0];
    const float* beta_p = (const float*)d_in[1];
    const float* eps    = (const float*)d_in[2];
    float*       out    = (float*)d_out;

    int N     = in_sizes[0] / 8;  // 4,000,000 points
    int block = 256;
    int grid  = (N + block - 1) / block;
    hipLaunchKernelGGL(e8_quant_kernel, dim3(grid), dim3(block), 0, stream,
                       x, beta_p, eps, out, N);
}